// Round 14
// baseline (16.742 us; speedup 1.0000x reference)
//
#include <hip/hip_runtime.h>

// Warp_Object bicubic warp: B=4, C=3, H=512, W=512, float32.
// Round 14: cross-tile software pipeline. Each block owns TWO vertically
// adjacent 32x32 tiles. Order: dx/dy loads -> BOTH tiles' coefficients
// (consumes dx/dy while only 4 vmem outstanding -> compiler waits are exact)
// -> issue stage(T0) -> issue stage(T1) -> vmcnt(3) [T1 in flight] + barrier
// -> stencil T0 + stores -> vmcnt(3) [stores in flight] + barrier -> stencil
// T1 + stores. T1's staging latency hides under T0's stencil; cold waits
// per px halved vs r13. Geometry per tile identical to r13 (44x48 staged,
// halo 6, 3 planes share coefficients).

constexpr int B = 4, C = 3, H = 512, W = 512;
constexpr int HW = H * W;              // 2^18
constexpr int TS = 32;                 // tile size (square)
constexpr int HALO = 6;
constexpr int RS = TS + 2 * HALO;      // 44 staged rows
constexpr int LSTC = 48;               // staged cols; %32=16 bank rotate
constexpr int CHR = LSTC / 4;          // 12 f4 chunks per staged row
constexpr int NCH = RS * CHR;          // 528 chunks per plane
constexpr int CPW = NCH / 16;          // 33 chunks per wave per plane
constexpr int TDW = RS * LSTC;         // 2112 dwords per plane
constexpr int NT = 1024;
constexpr int NB = 512;                // blocks; each does 2 tiles

typedef float f4 __attribute__((ext_vector_type(4)));
typedef f4 f4u __attribute__((aligned(4)));   // 4B-aligned float4 load

typedef const __attribute__((address_space(1))) void* gas_t;
typedef __attribute__((address_space(3))) void* las_t;

__device__ __forceinline__ void gload_lds16(const float* g, float* l) {
    __builtin_amdgcn_global_load_lds((gas_t)g, (las_t)l, 16, 0, 0);
}

struct Coef {
    float w0, w1, w2, w3;     // x-weights (image-edge clamp folded)
    float cy0, cy1, cy2, cy3; // y-coefficients
    int   lbase;              // LDS dword base
    bool  intile;
    int   y0, s;              // for the rare global fallback
};

__device__ __forceinline__ Coef make_coef(int x, int y, float dxv, float dyv,
                                          int yb, int cb) {
    Coef cf;
    float xm = (float)x + dxv;             // == ref up to ~3e-5 px rounding
    float ym = (float)y + dyv;
    float x0f = floorf(xm), y0f = floorf(ym);
    float ftx = xm - x0f, fty = ym - y0f;
    int x0 = (int)x0f, y0 = (int)y0f;
    int s  = min(max(x0 - 1, 0), W - 4);

    float tx2 = ftx * ftx, tx3 = tx2 * ftx;
    float cx0 = (-tx3 + 2.0f * tx2 - ftx) * 0.5f;
    float cx1 = (3.0f * tx3 - 5.0f * tx2 + 2.0f) * 0.5f;
    float cx2 = (-tx3 * 3.0f + 4.0f * tx2 + ftx) * 0.5f;
    float cx3 = 1.0f - (cx0 + cx1 + cx2);

    float ty2 = fty * fty, ty3 = ty2 * fty;
    cf.cy0 = (-ty3 + 2.0f * ty2 - fty) * 0.5f;
    cf.cy1 = (3.0f * ty3 - 5.0f * ty2 + 2.0f) * 0.5f;
    cf.cy2 = (-3.0f * ty3 + 4.0f * ty2 + fty) * 0.5f;
    cf.cy3 = 1.0f - (cf.cy0 + cf.cy1 + cf.cy2);

    if (__builtin_expect(x0 >= 1 && x0 <= W - 3, 1)) {
        cf.w0 = cx0; cf.w1 = cx1; cf.w2 = cx2; cf.w3 = cx3;
    } else {                               // fold image-edge taps into window
        float w0 = 0.f, w1 = 0.f, w2 = 0.f, w3 = 0.f;
        const float cxa[4] = {cx0, cx1, cx2, cx3};
#pragma unroll
        for (int o = 0; o < 4; ++o) {
            int xi = min(max(x0 - 1 + o, 0), W - 1);
            int e  = xi - s;               // 0..3 always
            float cc = cxa[o];
            w0 += (e == 0) ? cc : 0.f;
            w1 += (e == 1) ? cc : 0.f;
            w2 += (e == 2) ? cc : 0.f;
            w3 += (e == 3) ? cc : 0.f;
        }
        cf.w0 = w0; cf.w1 = w1; cf.w2 = w2; cf.w3 = w3;
    }

    unsigned rel = (unsigned)(y0 - (yb - HALO + 1));
    unsigned lsv = (unsigned)(s - cb);
    cf.intile = (rel <= (unsigned)(RS - 4)) & (lsv <= (unsigned)(LSTC - 4));
    cf.lbase  = (int)rel * LSTC + (int)lsv;
    cf.y0 = y0; cf.s = s;
    return cf;
}

__device__ __forceinline__ float stencil1(const float* __restrict__ tp,
                                          const Coef& cf,
                                          const float* __restrict__ plane) {
    if (__builtin_expect(cf.intile, 1)) {
        const float* rp = tp + cf.lbase;
        float r0 = cf.cy0 * (cf.w0 * rp[0] + cf.w1 * rp[1] + cf.w2 * rp[2] + cf.w3 * rp[3]);
        rp += LSTC;
        float r1 = cf.cy1 * (cf.w0 * rp[0] + cf.w1 * rp[1] + cf.w2 * rp[2] + cf.w3 * rp[3]);
        rp += LSTC;
        float r2 = cf.cy2 * (cf.w0 * rp[0] + cf.w1 * rp[1] + cf.w2 * rp[2] + cf.w3 * rp[3]);
        rp += LSTC;
        float r3 = cf.cy3 * (cf.w0 * rp[0] + cf.w1 * rp[1] + cf.w2 * rp[2] + cf.w3 * rp[3]);
        return (r0 + r1) + (r2 + r3);
    } else {
        // rare Gaussian-tail escape: always-correct global path
        const float cya[4] = {cf.cy0, cf.cy1, cf.cy2, cf.cy3};
        float acc = 0.f;
#pragma unroll
        for (int j = 0; j < 4; ++j) {
            int yi = min(max(cf.y0 - 1 + j, 0), H - 1);
            f4 v = *(const f4u*)(plane + yi * W + cf.s);
            acc += cya[j] * (cf.w0 * v.x + cf.w1 * v.y + cf.w2 * v.z + cf.w3 * v.w);
        }
        return acc;
    }
}

__device__ __forceinline__ void stage_tile(const float* __restrict__ img, int bd,
                                           int yb, int cb, float* dst,
                                           int wv, int lane) {
    if (lane < CPW) {                      // 33 active lanes; 3 instr per wave
        int chunk = wv * CPW + lane;       // < 528
        int r  = chunk / CHR;
        int c4 = (chunk - r * CHR) * 4;
        int sr = min(max(yb - HALO + r, 0), H - 1);   // y clamp == ref clamp
        int soff = sr * W + cb + c4;                  // always in-bounds
        const float* g0 = img + (size_t)bd * HW + soff;
        float* l0 = dst + chunk * 4;
        gload_lds16(g0,          l0);
        gload_lds16(g0 + 4 * HW, l0 + TDW);
        gload_lds16(g0 + 8 * HW, l0 + 2 * TDW);
    }
}

__global__ __launch_bounds__(NT, 8)
void warp_bicubic_2t(const float* __restrict__ img,
                     const float* __restrict__ dxp,
                     const float* __restrict__ dyp,
                     float* __restrict__ out)
{
    __shared__ float tile[2][C * TDW];         // 50,688 B -> 2 blocks/CU

    int b   = blockIdx.x;
    int swz = (b & 7) * (NB / 8) + (b >> 3);   // XCD-chunked, bijective (512=8*64)
    int bd  = swz >> 7;                        // displacement batch 0..3
    int rem = swz & 127;
    int typ = rem >> 4;                        // tile-pair row 0..7
    int txx = rem & 15;                        // tile col 0..15
    int xb  = txx * TS;
    int cb  = min(max(xb - HALO, 0), W - LSTC);
    int yb0 = typ * 2 * TS;
    int yb1 = yb0 + TS;

    int tid  = threadIdx.x;
    int wv   = tid >> 6;                       // 0..15
    int lane = tid & 63;
    int ry   = wv * 2 + (lane >> 5);           // 0..31
    int cidx = lane & 31;
    int x    = xb + cidx;
    int po0  = (yb0 + ry) * W + x;
    int po1  = (yb1 + ry) * W + x;

    // ---- 1) dx/dy for BOTH tiles (only vmem in flight during coeff math) --
    float dx0 = __builtin_nontemporal_load(dxp + bd * HW + po0);
    float dy0 = __builtin_nontemporal_load(dyp + bd * HW + po0);
    float dx1 = __builtin_nontemporal_load(dxp + bd * HW + po1);
    float dy1 = __builtin_nontemporal_load(dyp + bd * HW + po1);

    // ---- 2) both tiles' coefficients (compiler waits drain only dx/dy) ---
    Coef c0 = make_coef(x, yb0 + ry, dx0, dy0, yb0, cb);
    Coef c1 = make_coef(x, yb1 + ry, dx1, dy1, yb1, cb);
    __builtin_amdgcn_sched_barrier(0);

    // ---- 3) staging groups, exact per-wave vmem counts -------------------
    stage_tile(img, bd, yb0, cb, &tile[0][0], wv, lane);   // 3 vmem/wave
    __builtin_amdgcn_sched_barrier(0);
    stage_tile(img, bd, yb1, cb, &tile[1][0], wv, lane);   // 3 vmem/wave
    __builtin_amdgcn_sched_barrier(0);

    // ---- 4) gate T0: own T0 stages landed, T1's 3 stay in flight ---------
    asm volatile("s_waitcnt vmcnt(3)" ::: "memory");
    __builtin_amdgcn_sched_barrier(0);
    __builtin_amdgcn_s_barrier();

    // ---- 5) stencil T0 + NT stores ---------------------------------------
#pragma unroll
    for (int c = 0; c < C; ++c) {
        int kp = bd + 4 * c;
        float acc = stencil1(&tile[0][c * TDW], c0, img + (size_t)kp * HW);
        __builtin_nontemporal_store(acc, out + (size_t)kp * HW + po0);
    }

    // ---- 6) gate T1: T1 stages landed, T0's 3 stores stay in flight ------
    asm volatile("s_waitcnt vmcnt(3)" ::: "memory");
    __builtin_amdgcn_sched_barrier(0);
    __builtin_amdgcn_s_barrier();

    // ---- 7) stencil T1 + NT stores ---------------------------------------
#pragma unroll
    for (int c = 0; c < C; ++c) {
        int kp = bd + 4 * c;
        float acc = stencil1(&tile[1][c * TDW], c1, img + (size_t)kp * HW);
        __builtin_nontemporal_store(acc, out + (size_t)kp * HW + po1);
    }
}

extern "C" void kernel_launch(void* const* d_in, const int* in_sizes, int n_in,
                              void* d_out, int out_size, void* d_ws, size_t ws_size,
                              hipStream_t stream) {
    const float* img = (const float*)d_in[0];
    const float* dx  = (const float*)d_in[1];
    const float* dy  = (const float*)d_in[2];
    float* out = (float*)d_out;

    dim3 block(NT);
    dim3 grid(NB);   // 512 blocks x 2 tiles each
    hipLaunchKernelGGL(warp_bicubic_2t, grid, block, 0, stream,
                       img, dx, dy, out);
}